// Round 1
// 599.224 us; speedup vs baseline: 1.0747x; 1.0747x over previous
//
#include <hip/hip_runtime.h>

typedef __attribute__((ext_vector_type(8))) short short8;
typedef __attribute__((ext_vector_type(4))) float f32x4;

// ---------------- LDS map (ushort elements) ----------------
// phase 1 staging:  xs 256xLDX (20480 B) | ws 192xLDW (15360 B)   [reused as P slabs in phase 2]
// persistent:       q 256xLDQ | k 256xLDQ | v^T 64xLDV            (never touches HBM)
#define LDX 40
#define LDW 40
#define LDQ 72    // 144 B rows: 36 dwords -> bank stride 4, balanced for 16-row b128 reads
#define LDV 264   // 528 B rows: 132 dwords -> same balanced pattern
#define LDP 72

#define XS_OFF 0
#define WS_OFF 10240
#define Q_OFF  17920
#define K_OFF  36352
#define VT_OFF 54784
#define SMEM_ELEMS 71680   // 143360 B static LDS (<160 KiB/CU)

__device__ __forceinline__ ushort f2bf(float f) {
  unsigned u = __builtin_bit_cast(unsigned, f);
  u = (u + 0x7fffu + ((u >> 16) & 1u)) >> 16;   // RNE
  return (ushort)u;
}

// ---- kernel 0: pack Wq,Wk,Wv (fp32 [384][64]) -> Wt bf16 [192][384], row n = out channel
__global__ void prep_w(const float* __restrict__ Wk, const float* __restrict__ Wq,
                       const float* __restrict__ Wv, ushort* __restrict__ Wt) {
  int n = blockIdx.x;        // 0..191 : 0..63 Q, 64..127 K, 128..191 V
  int c = threadIdx.x;       // 0..383
  const float* src = (n < 64) ? Wq : ((n < 128) ? Wk : Wv);
  int h = n & 63;
  Wt[n * 384 + c] = f2bf(src[c * 64 + h]);
}

// ---- fused kernel: one block per batch b. 512 thr = 8 waves.
// Phase 1: QKV = x[b] @ W (acc in regs, 1-deep global->reg prefetch), results -> LDS.
// Phase 2: causal flash attention from LDS. Wave w owns query strips {w, 15-w} (balanced).
__global__ __launch_bounds__(512, 2) void fused(const float* __restrict__ x,
    const ushort* __restrict__ Wt, float* __restrict__ out) {
  __shared__ ushort sm[SMEM_ELEMS];
  const int tid = threadIdx.x;
  const int wave = tid >> 6;
  const int lane = tid & 63;
  const int quad = lane >> 4;
  const int l16 = lane & 15;
  const int b = blockIdx.x;
  const int wm = wave >> 2;   // channel half (96 ch)
  const int wn = wave & 3;    // token quarter (64 tok)

  // ================= phase 1: QKV GEMM (M=192 ch, N=256 tok, K=384) =================
  f32x4 acc[6][4];
#pragma unroll
  for (int i = 0; i < 6; ++i)
#pragma unroll
    for (int j = 0; j < 4; ++j) acc[i][j] = f32x4{0.f, 0.f, 0.f, 0.f};

  const float* xb = x + (long)b * 98304;   // 256*384
  int xrow[4], xc4[4];
#pragma unroll
  for (int i = 0; i < 4; ++i) { int idx = i * 512 + tid; xrow[i] = idx >> 3; xc4[i] = idx & 7; }
  const int wn0 = tid >> 2, wc0 = tid & 3;          // W row 0..127
  const int wn1 = (tid + 512) >> 2;                  // W row 128..191 (tid<256 only)

  ushort4 xh[4];
  uint4 w0, w1;

  auto LOADX = [&](int c0) {
#pragma unroll
    for (int i = 0; i < 4; ++i) {
      float4 f = *(const float4*)(xb + xrow[i] * 384 + c0 + xc4[i] * 4);
      ushort4 h;
      h.x = f2bf(f.x); h.y = f2bf(f.y); h.z = f2bf(f.z); h.w = f2bf(f.w);
      xh[i] = h;
    }
  };
  auto LOADW = [&](int c0) {
    w0 = *(const uint4*)(Wt + wn0 * 384 + c0 + wc0 * 8);
    if (tid < 256) w1 = *(const uint4*)(Wt + wn1 * 384 + c0 + wc0 * 8);
  };

  LOADX(0); LOADW(0);
  for (int t = 0; t < 12; ++t) {
    __syncthreads();                       // WAR: prev iter's LDS reads done
#pragma unroll
    for (int i = 0; i < 4; ++i)
      *(ushort4*)(&sm[XS_OFF + xrow[i] * LDX + xc4[i] * 4]) = xh[i];
    *(uint4*)(&sm[WS_OFF + wn0 * LDW + wc0 * 8]) = w0;
    if (tid < 256) *(uint4*)(&sm[WS_OFF + wn1 * LDW + wc0 * 8]) = w1;
    __syncthreads();
    if (t < 11) { LOADX((t + 1) * 32); LOADW((t + 1) * 32); }  // prefetch under MFMAs
    short8 bf[4];
#pragma unroll
    for (int tt = 0; tt < 4; ++tt)
      bf[tt] = *(const short8*)(&sm[XS_OFF + (wn * 64 + tt * 16 + l16) * LDX + quad * 8]);
#pragma unroll
    for (int mt = 0; mt < 6; ++mt) {
      short8 a = *(const short8*)(&sm[WS_OFF + (wm * 96 + mt * 16 + l16) * LDW + quad * 8]);
#pragma unroll
      for (int tt = 0; tt < 4; ++tt)
        acc[mt][tt] = __builtin_amdgcn_mfma_f32_16x16x32_bf16(a, bf[tt], acc[mt][tt], 0, 0, 0);
    }
  }

  // epilogue: acc -> q/k/v^T in LDS. D layout: ch = wm*96+mt*16+quad*4+r, tok = wn*64+tt*16+l16
#pragma unroll
  for (int mt = 0; mt < 6; ++mt) {
    const int chb = wm * 96 + mt * 16 + quad * 4;
#pragma unroll
    for (int tt = 0; tt < 4; ++tt) {
      const int tok = wn * 64 + tt * 16 + l16;
      if (chb < 64) {
        ushort4 h;
        h.x = f2bf(acc[mt][tt][0]); h.y = f2bf(acc[mt][tt][1]);
        h.z = f2bf(acc[mt][tt][2]); h.w = f2bf(acc[mt][tt][3]);
        *(ushort4*)(&sm[Q_OFF + tok * LDQ + chb]) = h;
      } else if (chb < 128) {
        ushort4 h;
        h.x = f2bf(acc[mt][tt][0]); h.y = f2bf(acc[mt][tt][1]);
        h.z = f2bf(acc[mt][tt][2]); h.w = f2bf(acc[mt][tt][3]);
        *(ushort4*)(&sm[K_OFF + tok * LDQ + (chb - 64)]) = h;
      } else {
#pragma unroll
        for (int r = 0; r < 4; ++r)
          sm[VT_OFF + (chb - 128 + r) * LDV + tok] = f2bf(acc[mt][tt][r]);
      }
    }
  }
  __syncthreads();   // q/k/v^T visible; staging region now free -> per-wave P slabs

  // ================= phase 2: causal flash attention from LDS =================
  const float sc = 0.125f * 1.44269504088896f;      // H^-0.5 * log2(e)
  ushort* psw = &sm[XS_OFF + wave * (16 * LDP)];    // per-wave P slab (2304 B)

  for (int si = 0; si < 2; ++si) {
    const int strip = (si == 0) ? wave : (15 - wave);   // 16-query strip index
    const int qs = strip * 16;
    const int nblk = strip;                // diagonal 16-key block index
    const int lastkb = nblk >> 2;          // last 64-key group

    short8 qf[2];
#pragma unroll
    for (int kk = 0; kk < 2; ++kk)
      qf[kk] = *(const short8*)(&sm[Q_OFF + (qs + l16) * LDQ + kk * 32 + quad * 8]);

    f32x4 O[4];
    float ms[4], ls[4];
#pragma unroll
    for (int ht = 0; ht < 4; ++ht) O[ht] = f32x4{0.f, 0.f, 0.f, 0.f};
#pragma unroll
    for (int r = 0; r < 4; ++r) { ms[r] = -3.0e38f; ls[r] = 0.f; }

    for (int kb = 0; kb <= lastkb; ++kb) {
      short8 kf[4][2], vf[2][4];
#pragma unroll
      for (int nt = 0; nt < 4; ++nt)
#pragma unroll
        for (int kk = 0; kk < 2; ++kk)
          kf[nt][kk] = *(const short8*)(&sm[K_OFF + (kb * 64 + nt * 16 + l16) * LDQ + kk * 32 + quad * 8]);
#pragma unroll
      for (int kk = 0; kk < 2; ++kk)
#pragma unroll
        for (int ht = 0; ht < 4; ++ht)
          vf[kk][ht] = *(const short8*)(&sm[VT_OFF + (ht * 16 + l16) * LDV + kb * 64 + kk * 32 + quad * 8]);

      const int gmax = nblk - kb * 4;      // highest valid nt in this group
      f32x4 S[4];
#pragma unroll
      for (int nt = 0; nt < 4; ++nt) {
        S[nt] = f32x4{0.f, 0.f, 0.f, 0.f};
        if (nt <= gmax) {
#pragma unroll
          for (int kk = 0; kk < 2; ++kk)
            S[nt] = __builtin_amdgcn_mfma_f32_16x16x32_bf16(qf[kk], kf[nt][kk], S[nt], 0, 0, 0);
        }
      }
      const bool lastg = (kb == lastkb);
      float s2[4][4];
#pragma unroll
      for (int nt = 0; nt < 4; ++nt)
#pragma unroll
        for (int r = 0; r < 4; ++r) {
          float v = S[nt][r] * sc;
          if (lastg && (kb * 64 + nt * 16 + l16) > (qs + quad * 4 + r)) v = -1.0e30f;
          s2[nt][r] = v;
        }
      float mnew[4], alpha[4], rsum[4];
#pragma unroll
      for (int r = 0; r < 4; ++r)
        mnew[r] = fmaxf(fmaxf(s2[0][r], s2[1][r]), fmaxf(s2[2][r], s2[3][r]));
#pragma unroll
      for (int off = 8; off > 0; off >>= 1)
#pragma unroll
        for (int r = 0; r < 4; ++r)
          mnew[r] = fmaxf(mnew[r], __shfl_xor(mnew[r], off, 64));
#pragma unroll
      for (int r = 0; r < 4; ++r) {
        mnew[r] = fmaxf(mnew[r], ms[r]);
        alpha[r] = exp2f(ms[r] - mnew[r]);
        ms[r] = mnew[r];
        rsum[r] = 0.f;
      }
#pragma unroll
      for (int nt = 0; nt < 4; ++nt)
#pragma unroll
        for (int r = 0; r < 4; ++r) {
          float p = exp2f(s2[nt][r] - mnew[r]);
          rsum[r] += p;
          psw[(quad * 4 + r) * LDP + nt * 16 + l16] = f2bf(p);
        }
#pragma unroll
      for (int off = 8; off > 0; off >>= 1)
#pragma unroll
        for (int r = 0; r < 4; ++r)
          rsum[r] += __shfl_xor(rsum[r], off, 64);
#pragma unroll
      for (int r = 0; r < 4; ++r)
        ls[r] = ls[r] * alpha[r] + rsum[r];
      // per-wave fence: P writes complete before A-frag reads (no block barrier in phase 2!)
      asm volatile("s_waitcnt lgkmcnt(0)" ::: "memory");
      __builtin_amdgcn_sched_barrier(0);
#pragma unroll
      for (int ht = 0; ht < 4; ++ht)
#pragma unroll
        for (int r = 0; r < 4; ++r) O[ht][r] *= alpha[r];
      short8 aP[2];
#pragma unroll
      for (int kk = 0; kk < 2; ++kk)
        aP[kk] = *(const short8*)(&psw[l16 * LDP + kk * 32 + quad * 8]);
#pragma unroll
      for (int kk = 0; kk < 2; ++kk)
#pragma unroll
        for (int ht = 0; ht < 4; ++ht)
          O[ht] = __builtin_amdgcn_mfma_f32_16x16x32_bf16(aP[kk], vf[kk][ht], O[ht], 0, 0, 0);
      // next iter's psw writes ordered after these reads by in-order DS + alias analysis
    }
    // epilogue: out fp32 [b][t][h]
#pragma unroll
    for (int r = 0; r < 4; ++r) {
      float inv = 1.0f / ls[r];
      long row = (long)b * 256 + qs + quad * 4 + r;
#pragma unroll
      for (int ht = 0; ht < 4; ++ht)
        out[row * 64 + ht * 16 + l16] = O[ht][r] * inv;
    }
  }
}

extern "C" void kernel_launch(void* const* d_in, const int* in_sizes, int n_in,
                              void* d_out, int out_size, void* d_ws, size_t ws_size,
                              hipStream_t stream) {
  const float* x  = (const float*)d_in[0];
  const float* Wk = (const float*)d_in[1];
  const float* Wq = (const float*)d_in[2];
  const float* Wv = (const float*)d_in[3];
  float* out = (float*)d_out;

  // ws layout: Wt bf16 [192*384] only (147456 B) — Q/K/V never leave LDS now
  ushort* Wt = (ushort*)d_ws;

  prep_w<<<dim3(192), dim3(384), 0, stream>>>(Wk, Wq, Wv, Wt);
  fused<<<dim3(1024), dim3(512), 0, stream>>>(x, Wt, out);
}